// Round 15
// baseline (189.396 us; speedup 1.0000x reference)
//
#include <hip/hip_runtime.h>

#define NN 65536
#define NE 262144
#define NG 2048

typedef __attribute__((ext_vector_type(16))) float f32x16;
typedef __attribute__((ext_vector_type(4)))  float f32x4;
typedef __attribute__((ext_vector_type(8)))  __bf16 bf16x8;

__device__ inline unsigned pack2(float a, float b) {
    return __builtin_amdgcn_perm(__float_as_uint(b), __float_as_uint(a), 0x07060302u);
}
__device__ inline float lof(float p) {
    return p - __uint_as_float(__float_as_uint(p) & 0xffff0000u);
}
__device__ inline bf16x8 asb(uint4 u) { return __builtin_bit_cast(bf16x8, u); }

// ---------------- setup: zero cnt/cur/agg1/agg2 + goffs + W-fragment prep ----
__global__ __launch_bounds__(256) void k_setup(
    const int* __restrict__ batch,
    const float* __restrict__ w2a, const float* __restrict__ b2a,
    const float* __restrict__ w2b, const float* __restrict__ b2c,
    int* __restrict__ cnt, int* __restrict__ cur, int* __restrict__ goffs,
    float* __restrict__ agg1, float* __restrict__ agg2,
    unsigned* __restrict__ f1, unsigned* __restrict__ f2)
{
    int t = blockIdx.x * 256 + threadIdx.x;      // 0..131071
    if (t < NN) { cnt[t] = 0; cur[t] = 0; }
    // zero agg1 (NN*32 f) + agg2 (NN*16 f) = 786432 float4
    {
        float4 z = make_float4(0.f, 0.f, 0.f, 0.f);
        float4* a1 = (float4*)agg1;
        float4* a2 = (float4*)agg2;
        for (int i = t; i < NN*8; i += 131072) a1[i] = z;
        for (int i = t; i < NN*4; i += 131072) a2[i] = z;
    }
    if (t <= NG) {
        int lo = 0, hi = NN;
        while (lo < hi) {
            int mid = (lo + hi) >> 1;
            if (batch[mid] < t) lo = mid + 1; else hi = mid;
        }
        goffs[t] = lo;
    }
    if (t < 17408) {
        int c = t / 8704;
        int r = t - c * 8704;
        int d = r & 3;
        int l = (r >> 2) & 63;
        int tt = (r >> 8) & 1;
        int s = r >> 9;
        if (c == 0) {   // conv1 table
            int n = l & 31, g = l >> 5;
            int j0 = 2*d;
            int c0 = (g*8 + j0)*32 + n;
            int c1 = c0 + 32;
            float a = (s < 16) ? w2a[s*512 + c0] : b2a[c0];
            float b = (s < 16) ? w2a[s*512 + c1] : b2a[c1];
            f1[r] = tt ? pack2(lof(a), lof(b)) : pack2(a, b);
        } else {        // conv2 table
            int n = l & 15, g = l >> 4;
            int j0 = 2*d;
            int c0 = (g*8 + j0)*16 + n;
            int c1 = c0 + 16;
            float a = (s < 16) ? w2b[s*512 + c0] : b2c[c0];
            float b = (s < 16) ? w2b[s*512 + c1] : b2c[c1];
            f2[r] = tt ? pack2(lof(a), lof(b)) : pack2(a, b);
        }
    }
}

// ---------------- fused hist + gate + attention pool (one block per graph) ---
__global__ __launch_bounds__(64) void k_gateatt(const float* __restrict__ x,
    const int* __restrict__ ei, int* __restrict__ cnt,
    const float* __restrict__ gw1, const float* __restrict__ gb1,
    const float* __restrict__ gw2, const float* __restrict__ gb2,
    const int* __restrict__ goffs, float* __restrict__ x_att)
{
    // edge histogram (fused; grid 2048x64 covers NE in 2 steps)
    {
        int gid = blockIdx.x * 64 + threadIdx.x;
        for (int e = gid; e < NE; e += NG*64)
            atomicAdd(&cnt[ei[NE + e]], 1);
    }
    __shared__ float sw[256];
    __shared__ float sb[16];
    __shared__ float sw2[16];
    __shared__ float sb2;
    __shared__ float gb[1024];
    const int g = blockIdx.x;
    const int lane = threadIdx.x;
    for (int i = lane; i < 256; i += 64) sw[i] = gw1[i];
    if (lane < 16) { sb[lane] = gb1[lane]; sw2[lane] = gw2[lane]; }
    if (lane == 0) sb2 = gb2[0];
    const int s = goffs[g], e = goffs[g + 1];
    const int cntg = e - s;
    if (cntg <= 0) {
        if (lane < 16) x_att[g*16 + lane] = 0.f;
        return;
    }
    const int cap = cntg < 1024 ? cntg : 1024;
    __syncthreads();
    for (int ii = lane; ii < cap; ii += 64) {
        const float4* xp = (const float4*)(x + (size_t)(s + ii) * 16);
        float xv[16];
#pragma unroll
        for (int i = 0; i < 4; ++i) {
            float4 tt = xp[i];
            xv[4*i] = tt.x; xv[4*i+1] = tt.y; xv[4*i+2] = tt.z; xv[4*i+3] = tt.w;
        }
        float gv = sb2;
#pragma unroll
        for (int j = 0; j < 16; ++j) {
            float a = sb[j];
#pragma unroll
            for (int i = 0; i < 16; ++i) a += xv[i] * sw[i*16 + j];
            gv += fmaxf(a, 0.f) * sw2[j];
        }
        gb[ii] = gv;
    }
    __syncthreads();
    float m = -1e30f;
    for (int ii = lane; ii < cap; ii += 64) m = fmaxf(m, gb[ii]);
#pragma unroll
    for (int d = 32; d; d >>= 1) m = fmaxf(m, __shfl_xor(m, d));
    float sum = 0.f;
    for (int ii = lane; ii < cap; ii += 64) {
        float ev = expf(gb[ii] - m);
        gb[ii] = ev;
        sum += ev;
    }
#pragma unroll
    for (int d = 32; d; d >>= 1) sum += __shfl_xor(sum, d);
    const float inv = 1.f / sum;
    __syncthreads();
    const int f = lane & 15, sub = lane >> 4;
    float acc = 0.f;
    for (int ii = sub; ii < cap; ii += 4)
        acc += gb[ii] * inv * x[(size_t)(s + ii)*16 + f];
    acc += __shfl_xor(acc, 16);
    acc += __shfl_xor(acc, 32);
    if (lane < 16) x_att[g*16 + f] = acc;
}

// ---------------- fused 3-level scan: one block, 1024 threads -----------------
__global__ __launch_bounds__(1024) void k_scan(const int* __restrict__ cnt,
    int* __restrict__ offs)
{
    __shared__ int ls[1024];
    const int t = threadIdx.x;
    const int base = t * 64;
    int sum = 0;
#pragma unroll 8
    for (int i = 0; i < 64; ++i) sum += cnt[base + i];
    ls[t] = sum;
    __syncthreads();
    for (int d = 1; d < 1024; d <<= 1) {
        int add = (t >= d) ? ls[t - d] : 0;
        __syncthreads();
        ls[t] += add;
        __syncthreads();
    }
    int run = ls[t] - sum;                    // exclusive prefix of chunk
#pragma unroll 8
    for (int i = 0; i < 64; ++i) {
        int c = cnt[base + i];
        offs[base + i] = run;
        run += c;
    }
    if (t == 1023) offs[NN] = run;            // == NE
}

// ---------------- scatter -----------------------------------------------------
__global__ __launch_bounds__(256) void k_scatter(const int* __restrict__ ei,
    const int* __restrict__ offs, int* __restrict__ cur, int2* __restrict__ epair)
{
    int e = blockIdx.x * 256 + threadIdx.x;
    if (e >= NE) return;
    int d = ei[NE + e];
    int pos = offs[d] + atomicAdd(&cur[d], 1);
    epair[pos] = make_int2(e, ei[e]);
}

// ---------------- layer1: fused conv1 (MFMA 32x32x16) + segmented reduce ------
// Block = 4 waves = 4 tiles = 128 sorted positions. Messages in LDS; interior
// node segments finalized in-block; border partials -> atomicAdd agg1.
__global__ __launch_bounds__(256) void k_layer1(
    const float* __restrict__ x, const float* __restrict__ ea,
    const int2* __restrict__ epair, const int* __restrict__ offs,
    const float* __restrict__ w1, const float* __restrict__ b1,
    const unsigned* __restrict__ bfrag,
    const float* __restrict__ root, const float* __restrict__ bias,
    float* __restrict__ h1, float* __restrict__ agg1)
{
    __shared__ uint4 s_tab[17*2*64];       // 34816 B
    __shared__ float s_msg[128*32];        // 16384 B  [edge-in-block][out]
    __shared__ float s_r[512];             // root [16][32]
    __shared__ float s_bias[32];
    __shared__ int   s_nlo, s_nhi;
    const int tid  = threadIdx.x;
    for (int i = tid; i < 17*2*64; i += 256) s_tab[i] = ((const uint4*)bfrag)[i];
    for (int i = tid; i < 512; i += 256) s_r[i] = root[i];
    if (tid < 32) s_bias[tid] = bias[tid];
    const int P0 = blockIdx.x * 128;
    if (tid == 0) {   // nlo: node containing P0; nhi: node containing P0+127
        int lo = 0, hi = NN;
        while (lo < hi) { int mid = (lo+hi)>>1; if (offs[mid+1] <= P0) lo = mid+1; else hi = mid; }
        s_nlo = lo;
        lo = 0; hi = NN;
        int PL = P0 + 127;
        while (lo < hi) { int mid = (lo+hi)>>1; if (offs[mid+1] <= PL) lo = mid+1; else hi = mid; }
        s_nhi = lo;
    }
    __syncthreads();

    // ---- phase 1: conv into LDS ----
    {
        const int lane = tid & 63;
        const int wid  = tid >> 6;
        const int m    = lane & 31;
        const int g    = lane >> 5;
        const int p    = P0 + wid*32 + m;
        const int2 ep  = epair[p];
        const int e    = ep.x, src = ep.y;

        float xs[8];
        {
            const float4* xp = (const float4*)(x + (size_t)src*16 + g*8);
            float4 aa = xp[0], bb = xp[1];
            xs[0]=aa.x; xs[1]=aa.y; xs[2]=aa.z; xs[3]=aa.w;
            xs[4]=bb.x; xs[5]=bb.y; xs[6]=bb.z; xs[7]=bb.w;
        }
        float h[17];
        {
            const float2 e01 = *(const float2*)(ea + (size_t)e*6);
            const float2 e23 = *(const float2*)(ea + (size_t)e*6 + 2);
            const float2 e45 = *(const float2*)(ea + (size_t)e*6 + 4);
            const float a0=e01.x, a1=e01.y, a2=e23.x, a3=e23.y, a4=e45.x, a5=e45.y;
#pragma unroll
            for (int j = 0; j < 16; ++j) {
                float c = b1[j];
                c += a0*w1[0*16+j]; c += a1*w1[1*16+j]; c += a2*w1[2*16+j];
                c += a3*w1[3*16+j]; c += a4*w1[4*16+j]; c += a5*w1[5*16+j];
                h[j] = fmaxf(c, 0.f);
            }
            h[16] = 1.f;
        }

        f32x16 acc0 = {}, acc1 = {};
#pragma unroll
        for (int s = 0; s < 17; ++s) {
            const float hs = h[s];
            float p0 = hs*xs[0], p1 = hs*xs[1], p2 = hs*xs[2], p3 = hs*xs[3];
            float p4 = hs*xs[4], p5 = hs*xs[5], p6 = hs*xs[6], p7 = hs*xs[7];
            uint4 uh = { pack2(p0,p1), pack2(p2,p3), pack2(p4,p5), pack2(p6,p7) };
            uint4 ul = { pack2(lof(p0),lof(p1)), pack2(lof(p2),lof(p3)),
                         pack2(lof(p4),lof(p5)), pack2(lof(p6),lof(p7)) };
            uint4 wh = s_tab[(s*2+0)*64 + lane];
            uint4 wl = s_tab[(s*2+1)*64 + lane];
            if (s & 1) {
                acc1 = __builtin_amdgcn_mfma_f32_32x32x16_bf16(asb(uh), asb(wh), acc1, 0, 0, 0);
                acc1 = __builtin_amdgcn_mfma_f32_32x32x16_bf16(asb(uh), asb(wl), acc1, 0, 0, 0);
                acc1 = __builtin_amdgcn_mfma_f32_32x32x16_bf16(asb(ul), asb(wh), acc1, 0, 0, 0);
            } else {
                acc0 = __builtin_amdgcn_mfma_f32_32x32x16_bf16(asb(uh), asb(wh), acc0, 0, 0, 0);
                acc0 = __builtin_amdgcn_mfma_f32_32x32x16_bf16(asb(uh), asb(wl), acc0, 0, 0, 0);
                acc0 = __builtin_amdgcn_mfma_f32_32x32x16_bf16(asb(ul), asb(wh), acc0, 0, 0, 0);
            }
        }
        float* mbase = s_msg + wid*32*32;
        const int rb = g*4;
#pragma unroll
        for (int r = 0; r < 16; ++r) {
            int mr = (r&3) + 8*(r>>2) + rb;          // edge-in-tile
            mbase[mr*32 + m] = acc0[r] + acc1[r];    // col = out channel
        }
    }
    __syncthreads();

    // ---- phase 2: segmented reduce + epilogue ----
    {
        const int nlo = s_nlo, nhi = s_nhi;
        const int items = (nhi - nlo + 1) * 8;
        const float4* s_r4 = (const float4*)s_r;
        const float4* m4 = (const float4*)s_msg;     // [128][8] float4
        for (int it = tid; it < items; it += 256) {
            const int n = nlo + (it >> 3);
            const int q = it & 7;
            const int os = offs[n], oe = offs[n+1];
            const int ss = os > P0 ? os : P0;
            const int se = oe < P0+128 ? oe : P0+128;
            if (ss >= se) continue;
            float4 acc = make_float4(0.f, 0.f, 0.f, 0.f);
            for (int p = ss; p < se; ++p) {
                float4 mr = m4[(p - P0)*8 + q];
                acc.x += mr.x; acc.y += mr.y; acc.z += mr.z; acc.w += mr.w;
            }
            const bool interior = (os >= P0) && (oe <= P0 + 128);
            if (interior) {
                acc.x += s_bias[4*q]; acc.y += s_bias[4*q+1];
                acc.z += s_bias[4*q+2]; acc.w += s_bias[4*q+3];
                const float4* xp4 = (const float4*)(x + (size_t)n * 16);
#pragma unroll
                for (int ii = 0; ii < 4; ++ii) {
                    float4 xv = xp4[ii];
                    float4 w0 = s_r4[(ii*4+0)*8 + q];
                    float4 w1v = s_r4[(ii*4+1)*8 + q];
                    float4 w2v = s_r4[(ii*4+2)*8 + q];
                    float4 w3 = s_r4[(ii*4+3)*8 + q];
                    acc.x += xv.x*w0.x + xv.y*w1v.x + xv.z*w2v.x + xv.w*w3.x;
                    acc.y += xv.x*w0.y + xv.y*w1v.y + xv.z*w2v.y + xv.w*w3.y;
                    acc.z += xv.x*w0.z + xv.y*w1v.z + xv.z*w2v.z + xv.w*w3.z;
                    acc.w += xv.x*w0.w + xv.y*w1v.w + xv.z*w2v.w + xv.w*w3.w;
                }
                acc.x = fmaxf(acc.x, 0.f); acc.y = fmaxf(acc.y, 0.f);
                acc.z = fmaxf(acc.z, 0.f); acc.w = fmaxf(acc.w, 0.f);
                ((float4*)(h1 + (size_t)n * 32))[q] = acc;
            } else {
                float* ap = agg1 + (size_t)n * 32 + q*4;
                atomicAdd(ap + 0, acc.x);
                atomicAdd(ap + 1, acc.y);
                atomicAdd(ap + 2, acc.z);
                atomicAdd(ap + 3, acc.w);
            }
        }
    }
}

// ---------------- fix1: finalize border + zero-degree nodes -------------------
__global__ __launch_bounds__(256) void k_fix1(
    const int* __restrict__ offs, const float* __restrict__ agg1,
    const float* __restrict__ x, const float* __restrict__ root,
    const float* __restrict__ bias, float* __restrict__ h1)
{
    __shared__ float s_r[512];
    __shared__ float s_b[32];
    int tid = threadIdx.x;
    for (int i = tid; i < 512; i += 256) s_r[i] = root[i];
    if (tid < 32) s_b[tid] = bias[tid];
    __syncthreads();
    int gid = blockIdx.x * 256 + tid;
    int n = gid >> 3, q = gid & 7;
    int os = offs[n], oe = offs[n+1];
    bool interior = (oe > os) && ((os >> 7) == ((oe - 1) >> 7));
    if (interior) return;                       // already written by its block
    float4 acc = ((const float4*)(agg1 + (size_t)n * 32))[q];
    acc.x += s_b[4*q]; acc.y += s_b[4*q+1]; acc.z += s_b[4*q+2]; acc.w += s_b[4*q+3];
    const float4* s_r4 = (const float4*)s_r;
    const float4* xp4 = (const float4*)(x + (size_t)n * 16);
#pragma unroll
    for (int ii = 0; ii < 4; ++ii) {
        float4 xv = xp4[ii];
        float4 w0 = s_r4[(ii*4+0)*8 + q];
        float4 w1v = s_r4[(ii*4+1)*8 + q];
        float4 w2v = s_r4[(ii*4+2)*8 + q];
        float4 w3 = s_r4[(ii*4+3)*8 + q];
        acc.x += xv.x*w0.x + xv.y*w1v.x + xv.z*w2v.x + xv.w*w3.x;
        acc.y += xv.x*w0.y + xv.y*w1v.y + xv.z*w2v.y + xv.w*w3.y;
        acc.z += xv.x*w0.z + xv.y*w1v.z + xv.z*w2v.z + xv.w*w3.z;
        acc.w += xv.x*w0.w + xv.y*w1v.w + xv.z*w2v.w + xv.w*w3.w;
    }
    acc.x = fmaxf(acc.x, 0.f); acc.y = fmaxf(acc.y, 0.f);
    acc.z = fmaxf(acc.z, 0.f); acc.w = fmaxf(acc.w, 0.f);
    ((float4*)(h1 + (size_t)n * 32))[q] = acc;
}

// ---------------- layer2: fused conv2 (h-hoisted 16x16x32) + seg reduce -------
// Block = 4 waves = 4 tiles = 64 sorted positions.
__global__ __launch_bounds__(256) void k_layer2(
    const float* __restrict__ x, const float* __restrict__ ea,
    const int2* __restrict__ epair, const int* __restrict__ offs,
    const float* __restrict__ w1, const float* __restrict__ b1,
    const unsigned* __restrict__ bfrag,
    const float* __restrict__ root, const float* __restrict__ bias,
    float* __restrict__ h2, float* __restrict__ agg2)
{
    __shared__ uint4 s_tab[17*2*64];       // 34816 B
    __shared__ float s_msg[64*16];         // 4096 B  [edge-in-block][out]
    __shared__ float s_r[512];             // root [32][16]
    __shared__ float s_bias[16];
    __shared__ int   s_nlo, s_nhi;
    const int tid  = threadIdx.x;
    for (int i = tid; i < 17*2*64; i += 256) s_tab[i] = ((const uint4*)bfrag)[i];
    for (int i = tid; i < 512; i += 256) s_r[i] = root[i];
    if (tid < 16) s_bias[tid] = bias[tid];
    const int P0 = blockIdx.x * 64;
    if (tid == 0) {
        int lo = 0, hi = NN;
        while (lo < hi) { int mid = (lo+hi)>>1; if (offs[mid+1] <= P0) lo = mid+1; else hi = mid; }
        s_nlo = lo;
        lo = 0; hi = NN;
        int PL = P0 + 63;
        while (lo < hi) { int mid = (lo+hi)>>1; if (offs[mid+1] <= PL) lo = mid+1; else hi = mid; }
        s_nhi = lo;
    }
    __syncthreads();

    // ---- phase 1: conv into LDS ----
    {
        const int lane = tid & 63;
        const int wid  = tid >> 6;
        const int m    = lane & 15;
        const int g    = lane >> 4;
        const int p    = P0 + wid*16 + m;
        const int2 ep  = epair[p];
        const int e    = ep.x, src = ep.y;

        uint4 xh, xl;
        {
            const float4* xp = (const float4*)(x + (size_t)src*32 + g*8);
            float4 aa = xp[0], bb = xp[1];
            xh = (uint4){ pack2(aa.x,aa.y), pack2(aa.z,aa.w), pack2(bb.x,bb.y), pack2(bb.z,bb.w) };
            xl = (uint4){ pack2(lof(aa.x),lof(aa.y)), pack2(lof(aa.z),lof(aa.w)),
                          pack2(lof(bb.x),lof(bb.y)), pack2(lof(bb.z),lof(bb.w)) };
        }
        float h[17];
        {
            const float2 e01 = *(const float2*)(ea + (size_t)e*6);
            const float2 e23 = *(const float2*)(ea + (size_t)e*6 + 2);
            const float2 e45 = *(const float2*)(ea + (size_t)e*6 + 4);
            const float a0=e01.x, a1=e01.y, a2=e23.x, a3=e23.y, a4=e45.x, a5=e45.y;
#pragma unroll
            for (int j = 0; j < 16; ++j) {
                float c = b1[j];
                c += a0*w1[0*16+j]; c += a1*w1[1*16+j]; c += a2*w1[2*16+j];
                c += a3*w1[3*16+j]; c += a4*w1[4*16+j]; c += a5*w1[5*16+j];
                h[j] = fmaxf(c, 0.f);
            }
            h[16] = 1.f;
        }

        f32x4 macc = {};
#pragma unroll
        for (int s = 0; s < 17; ++s) {
            uint4 wh = s_tab[(s*2+0)*64 + lane];
            uint4 wl = s_tab[(s*2+1)*64 + lane];
            f32x4 t = {};
            t = __builtin_amdgcn_mfma_f32_16x16x32_bf16(asb(wh), asb(xh), t, 0, 0, 0);
            t = __builtin_amdgcn_mfma_f32_16x16x32_bf16(asb(wl), asb(xh), t, 0, 0, 0);
            t = __builtin_amdgcn_mfma_f32_16x16x32_bf16(asb(wh), asb(xl), t, 0, 0, 0);
            const float hs = h[s];
            macc.x += hs*t.x; macc.y += hs*t.y; macc.z += hs*t.z; macc.w += hs*t.w;
        }
        // D row o = g*4+r, col edge m -> LDS [edge][o]
        float* lw = s_msg + (wid*16 + m)*16;
        lw[g*4 + 0] = macc.x;
        lw[g*4 + 1] = macc.y;
        lw[g*4 + 2] = macc.z;
        lw[g*4 + 3] = macc.w;
    }
    __syncthreads();

    // ---- phase 2: segmented reduce + epilogue ----
    {
        const int nlo = s_nlo, nhi = s_nhi;
        const int items = (nhi - nlo + 1) * 4;
        const float4* s_r4 = (const float4*)s_r;
        const float4* m4 = (const float4*)s_msg;     // [64][4] float4
        for (int it = tid; it < items; it += 256) {
            const int n = nlo + (it >> 2);
            const int q = it & 3;
            const int os = offs[n], oe = offs[n+1];
            const int ss = os > P0 ? os : P0;
            const int se = oe < P0+64 ? oe : P0+64;
            if (ss >= se) continue;
            float4 acc = make_float4(0.f, 0.f, 0.f, 0.f);
            for (int p = ss; p < se; ++p) {
                float4 mr = m4[(p - P0)*4 + q];
                acc.x += mr.x; acc.y += mr.y; acc.z += mr.z; acc.w += mr.w;
            }
            const bool interior = (os >= P0) && (oe <= P0 + 64);
            if (interior) {
                acc.x += s_bias[4*q]; acc.y += s_bias[4*q+1];
                acc.z += s_bias[4*q+2]; acc.w += s_bias[4*q+3];
                const float4* xp4 = (const float4*)(x + (size_t)n * 32);
#pragma unroll
                for (int ii = 0; ii < 8; ++ii) {
                    float4 xv = xp4[ii];
                    float4 w0 = s_r4[(ii*4+0)*4 + q];
                    float4 w1v = s_r4[(ii*4+1)*4 + q];
                    float4 w2v = s_r4[(ii*4+2)*4 + q];
                    float4 w3 = s_r4[(ii*4+3)*4 + q];
                    acc.x += xv.x*w0.x + xv.y*w1v.x + xv.z*w2v.x + xv.w*w3.x;
                    acc.y += xv.x*w0.y + xv.y*w1v.y + xv.z*w2v.y + xv.w*w3.y;
                    acc.z += xv.x*w0.z + xv.y*w1v.z + xv.z*w2v.z + xv.w*w3.z;
                    acc.w += xv.x*w0.w + xv.y*w1v.w + xv.z*w2v.w + xv.w*w3.w;
                }
                acc.x = fmaxf(acc.x, 0.f); acc.y = fmaxf(acc.y, 0.f);
                acc.z = fmaxf(acc.z, 0.f); acc.w = fmaxf(acc.w, 0.f);
                ((float4*)(h2 + (size_t)n * 16))[q] = acc;
            } else {
                float* ap = agg2 + (size_t)n * 16 + q*4;
                atomicAdd(ap + 0, acc.x);
                atomicAdd(ap + 1, acc.y);
                atomicAdd(ap + 2, acc.z);
                atomicAdd(ap + 3, acc.w);
            }
        }
    }
}

// ---------------- fix2: finalize border + zero-degree nodes -------------------
__global__ __launch_bounds__(256) void k_fix2(
    const int* __restrict__ offs, const float* __restrict__ agg2,
    const float* __restrict__ h1, const float* __restrict__ root,
    const float* __restrict__ bias, float* __restrict__ h2)
{
    __shared__ float s_r[512];
    __shared__ float s_b[16];
    int tid = threadIdx.x;
    for (int i = tid; i < 512; i += 256) s_r[i] = root[i];
    if (tid < 16) s_b[tid] = bias[tid];
    __syncthreads();
    int gid = blockIdx.x * 256 + tid;
    int n = gid >> 2, q = gid & 3;
    int os = offs[n], oe = offs[n+1];
    bool interior = (oe > os) && ((os >> 6) == ((oe - 1) >> 6));
    if (interior) return;
    float4 acc = ((const float4*)(agg2 + (size_t)n * 16))[q];
    acc.x += s_b[4*q]; acc.y += s_b[4*q+1]; acc.z += s_b[4*q+2]; acc.w += s_b[4*q+3];
    const float4* s_r4 = (const float4*)s_r;
    const float4* xp4 = (const float4*)(h1 + (size_t)n * 32);
#pragma unroll
    for (int ii = 0; ii < 8; ++ii) {
        float4 xv = xp4[ii];
        float4 w0 = s_r4[(ii*4+0)*4 + q];
        float4 w1v = s_r4[(ii*4+1)*4 + q];
        float4 w2v = s_r4[(ii*4+2)*4 + q];
        float4 w3 = s_r4[(ii*4+3)*4 + q];
        acc.x += xv.x*w0.x + xv.y*w1v.x + xv.z*w2v.x + xv.w*w3.x;
        acc.y += xv.x*w0.y + xv.y*w1v.y + xv.z*w2v.y + xv.w*w3.y;
        acc.z += xv.x*w0.z + xv.y*w1v.z + xv.z*w2v.z + xv.w*w3.z;
        acc.w += xv.x*w0.w + xv.y*w1v.w + xv.z*w2v.w + xv.w*w3.w;
    }
    acc.x = fmaxf(acc.x, 0.f); acc.y = fmaxf(acc.y, 0.f);
    acc.z = fmaxf(acc.z, 0.f); acc.w = fmaxf(acc.w, 0.f);
    ((float4*)(h2 + (size_t)n * 16))[q] = acc;
}

// ---------------- mean pool + concat + head ----------------------------------
__global__ __launch_bounds__(64) void k_head(
    const float* __restrict__ h2, const float* __restrict__ x_att,
    const int* __restrict__ goffs,
    const float* __restrict__ l1w, const float* __restrict__ l1b,
    const float* __restrict__ l2w, const float* __restrict__ l2b,
    float* __restrict__ out)
{
    int g = blockIdx.x;
    int lane = threadIdx.x;
    int s = goffs[g], e = goffs[g + 1];
    __shared__ float v[32];
    __shared__ float hmid[8];
    int f = lane & 15, sub = lane >> 4;
    float acc = 0.f;
    for (int i = s + sub; i < e; i += 4) acc += h2[(size_t)i*16 + f];
    acc += __shfl_xor(acc, 16);
    acc += __shfl_xor(acc, 32);
    float cnt = fmaxf((float)(e - s), 1.0f);
    if (lane < 16) {
        v[lane]      = acc / cnt;
        v[16 + lane] = x_att[g*16 + lane];
    }
    __syncthreads();
    if (lane < 8) {
        float a = l1b[lane];
#pragma unroll
        for (int i = 0; i < 32; ++i) a += v[i] * l1w[i*8 + lane];
        hmid[lane] = a;
    }
    __syncthreads();
    if (lane == 0) {
        float a = l2b[0];
#pragma unroll
        for (int j = 0; j < 8; ++j) a += hmid[j] * l2w[j];
        out[g] = a;
    }
}

extern "C" void kernel_launch(void* const* d_in, const int* in_sizes, int n_in,
                              void* d_out, int out_size, void* d_ws, size_t ws_size,
                              hipStream_t stream) {
    const float* x_p    = (const float*)d_in[0];
    const float* ea_p   = (const float*)d_in[2];
    const int*   ei     = (const int*)d_in[4];
    const int*   batch  = (const int*)d_in[5];
    const float* nn1_w1 = (const float*)d_in[6];
    const float* nn1_b1 = (const float*)d_in[7];
    const float* nn1_w2 = (const float*)d_in[8];
    const float* nn1_b2 = (const float*)d_in[9];
    const float* root1  = (const float*)d_in[10];
    const float* bias1  = (const float*)d_in[11];
    const float* nn2_w1 = (const float*)d_in[12];
    const float* nn2_b1 = (const float*)d_in[13];
    const float* nn2_w2 = (const float*)d_in[14];
    const float* nn2_b2 = (const float*)d_in[15];
    const float* root2  = (const float*)d_in[16];
    const float* bias2  = (const float*)d_in[17];
    const float* gw1    = (const float*)d_in[18];
    const float* gb1    = (const float*)d_in[19];
    const float* gw2    = (const float*)d_in[20];
    const float* gb2    = (const float*)d_in[21];
    const float* l1w    = (const float*)d_in[22];
    const float* l1b    = (const float*)d_in[23];
    const float* l2w    = (const float*)d_in[24];
    const float* l2b    = (const float*)d_in[25];

    // -------- workspace layout (~28 MB) --------
    float*    h1     = (float*)d_ws;                     // NN*32
    float*    h2     = h1 + (size_t)NN * 32;             // NN*16
    float*    agg1   = h2 + (size_t)NN * 16;             // NN*32
    float*    agg2   = agg1 + (size_t)NN * 32;           // NN*16
    float*    x_att  = agg2 + (size_t)NN * 16;           // NG*16
    int*      goffs  = (int*)(x_att + (size_t)NG * 16);  // 2052
    int*      offs   = goffs + 2052;                     // 65540
    int*      cnt    = offs + 65540;                     // NN
    int*      cur    = cnt + NN;                         // NN
    int2*     epair  = (int2*)(cur + NN);                // NE int2
    unsigned* bfrag1 = (unsigned*)(epair + NE);          // 8704
    unsigned* bfrag2 = bfrag1 + 8704;                    // 8704

    // 1. setup: zero cnt/cur/agg1/agg2, goffs, W fragments
    k_setup<<<512, 256, 0, stream>>>(batch, nn1_w2, nn1_b2, nn2_w2, nn2_b2,
                                     cnt, cur, goffs, agg1, agg2, bfrag1, bfrag2);
    // 2. fused hist + gate + attention pool
    k_gateatt<<<NG, 64, 0, stream>>>(x_p, ei, cnt, gw1, gb1, gw2, gb2, goffs, x_att);
    // 3. fused scan
    k_scan<<<1, 1024, 0, stream>>>(cnt, offs);
    // 4. scatter
    k_scatter<<<NE/256, 256, 0, stream>>>(ei, offs, cur, epair);
    // 5-6. layer 1 (fused conv+reduce) + fix
    k_layer1<<<NE/128, 256, 0, stream>>>(x_p, ea_p, epair, offs,
                                         nn1_w1, nn1_b1, bfrag1, root1, bias1, h1, agg1);
    k_fix1<<<NN*8/256, 256, 0, stream>>>(offs, agg1, x_p, root1, bias1, h1);
    // 7-8. layer 2 (fused conv+reduce) + fix
    k_layer2<<<NE/64, 256, 0, stream>>>(h1, ea_p, epair, offs,
                                        nn2_w1, nn2_b1, bfrag2, root2, bias2, h2, agg2);
    k_fix2<<<NN*4/256, 256, 0, stream>>>(offs, agg2, h1, root2, bias2, h2);
    // 9. head
    k_head<<<NG, 64, 0, stream>>>(h2, x_att, goffs, l1w, l1b, l2w, l2b, (float*)d_out);
}

// Round 16
// 173.165 us; speedup vs baseline: 1.0937x; 1.0937x over previous
//
#include <hip/hip_runtime.h>

#define NN 65536
#define NE 262144
#define NG 2048

typedef __attribute__((ext_vector_type(16))) float f32x16;
typedef __attribute__((ext_vector_type(4)))  float f32x4;
typedef __attribute__((ext_vector_type(8)))  __bf16 bf16x8;

__device__ inline unsigned pack2(float a, float b) {
    return __builtin_amdgcn_perm(__float_as_uint(b), __float_as_uint(a), 0x07060302u);
}
__device__ inline float lof(float p) {
    return p - __uint_as_float(__float_as_uint(p) & 0xffff0000u);
}
__device__ inline bf16x8 asb(uint4 u) { return __builtin_bit_cast(bf16x8, u); }

// ---------------- setup: zero cnt/cur/agg1/agg2 + goffs + W-fragment prep ----
__global__ __launch_bounds__(256) void k_setup(
    const int* __restrict__ batch,
    const float* __restrict__ w2a, const float* __restrict__ b2a,
    const float* __restrict__ w2b, const float* __restrict__ b2c,
    int* __restrict__ cnt, int* __restrict__ cur, int* __restrict__ goffs,
    float* __restrict__ agg1, float* __restrict__ agg2,
    unsigned* __restrict__ f1, unsigned* __restrict__ f2)
{
    int t = blockIdx.x * 256 + threadIdx.x;      // 0..131071
    if (t < NN) { cnt[t] = 0; cur[t] = 0; }
    {
        float4 z = make_float4(0.f, 0.f, 0.f, 0.f);
        float4* a1 = (float4*)agg1;
        float4* a2 = (float4*)agg2;
        for (int i = t; i < NN*8; i += 131072) a1[i] = z;
        for (int i = t; i < NN*4; i += 131072) a2[i] = z;
    }
    if (t <= NG) {
        int lo = 0, hi = NN;
        while (lo < hi) {
            int mid = (lo + hi) >> 1;
            if (batch[mid] < t) lo = mid + 1; else hi = mid;
        }
        goffs[t] = lo;
    }
    if (t < 17408) {
        int c = t / 8704;
        int r = t - c * 8704;
        int d = r & 3;
        int l = (r >> 2) & 63;
        int tt = (r >> 8) & 1;
        int s = r >> 9;
        if (c == 0) {   // conv1 table
            int n = l & 31, g = l >> 5;
            int j0 = 2*d;
            int c0 = (g*8 + j0)*32 + n;
            int c1 = c0 + 32;
            float a = (s < 16) ? w2a[s*512 + c0] : b2a[c0];
            float b = (s < 16) ? w2a[s*512 + c1] : b2a[c1];
            f1[r] = tt ? pack2(lof(a), lof(b)) : pack2(a, b);
        } else {        // conv2 table
            int n = l & 15, g = l >> 4;
            int j0 = 2*d;
            int c0 = (g*8 + j0)*16 + n;
            int c1 = c0 + 16;
            float a = (s < 16) ? w2b[s*512 + c0] : b2c[c0];
            float b = (s < 16) ? w2b[s*512 + c1] : b2c[c1];
            f2[r] = tt ? pack2(lof(a), lof(b)) : pack2(a, b);
        }
    }
}

// ---------------- fused hist + gate + attention pool (one block per graph) ---
__global__ __launch_bounds__(64) void k_gateatt(const float* __restrict__ x,
    const int* __restrict__ ei, int* __restrict__ cnt,
    const float* __restrict__ gw1, const float* __restrict__ gb1,
    const float* __restrict__ gw2, const float* __restrict__ gb2,
    const int* __restrict__ goffs, float* __restrict__ x_att)
{
    {
        int gid = blockIdx.x * 64 + threadIdx.x;
        for (int e = gid; e < NE; e += NG*64)
            atomicAdd(&cnt[ei[NE + e]], 1);
    }
    __shared__ float sw[256];
    __shared__ float sb[16];
    __shared__ float sw2[16];
    __shared__ float sb2;
    __shared__ float gb[1024];
    const int g = blockIdx.x;
    const int lane = threadIdx.x;
    for (int i = lane; i < 256; i += 64) sw[i] = gw1[i];
    if (lane < 16) { sb[lane] = gb1[lane]; sw2[lane] = gw2[lane]; }
    if (lane == 0) sb2 = gb2[0];
    const int s = goffs[g], e = goffs[g + 1];
    const int cntg = e - s;
    if (cntg <= 0) {
        if (lane < 16) x_att[g*16 + lane] = 0.f;
        return;
    }
    const int cap = cntg < 1024 ? cntg : 1024;
    __syncthreads();
    for (int ii = lane; ii < cap; ii += 64) {
        const float4* xp = (const float4*)(x + (size_t)(s + ii) * 16);
        float xv[16];
#pragma unroll
        for (int i = 0; i < 4; ++i) {
            float4 tt = xp[i];
            xv[4*i] = tt.x; xv[4*i+1] = tt.y; xv[4*i+2] = tt.z; xv[4*i+3] = tt.w;
        }
        float gv = sb2;
#pragma unroll
        for (int j = 0; j < 16; ++j) {
            float a = sb[j];
#pragma unroll
            for (int i = 0; i < 16; ++i) a += xv[i] * sw[i*16 + j];
            gv += fmaxf(a, 0.f) * sw2[j];
        }
        gb[ii] = gv;
    }
    __syncthreads();
    float m = -1e30f;
    for (int ii = lane; ii < cap; ii += 64) m = fmaxf(m, gb[ii]);
#pragma unroll
    for (int d = 32; d; d >>= 1) m = fmaxf(m, __shfl_xor(m, d));
    float sum = 0.f;
    for (int ii = lane; ii < cap; ii += 64) {
        float ev = expf(gb[ii] - m);
        gb[ii] = ev;
        sum += ev;
    }
#pragma unroll
    for (int d = 32; d; d >>= 1) sum += __shfl_xor(sum, d);
    const float inv = 1.f / sum;
    __syncthreads();
    const int f = lane & 15, sub = lane >> 4;
    float acc = 0.f;
    for (int ii = sub; ii < cap; ii += 4)
        acc += gb[ii] * inv * x[(size_t)(s + ii)*16 + f];
    acc += __shfl_xor(acc, 16);
    acc += __shfl_xor(acc, 32);
    if (lane < 16) x_att[g*16 + f] = acc;
}

// ---------------- fused 3-level scan: one block, 1024 threads -----------------
__global__ __launch_bounds__(1024) void k_scan(const int* __restrict__ cnt,
    int* __restrict__ offs)
{
    __shared__ int ls[1024];
    const int t = threadIdx.x;
    const int base = t * 64;
    int sum = 0;
#pragma unroll 8
    for (int i = 0; i < 64; ++i) sum += cnt[base + i];
    ls[t] = sum;
    __syncthreads();
    for (int d = 1; d < 1024; d <<= 1) {
        int add = (t >= d) ? ls[t - d] : 0;
        __syncthreads();
        ls[t] += add;
        __syncthreads();
    }
    int run = ls[t] - sum;
#pragma unroll 8
    for (int i = 0; i < 64; ++i) {
        int c = cnt[base + i];
        offs[base + i] = run;
        run += c;
    }
    if (t == 1023) offs[NN] = run;
}

// ---------------- scatter -----------------------------------------------------
__global__ __launch_bounds__(256) void k_scatter(const int* __restrict__ ei,
    const int* __restrict__ offs, int* __restrict__ cur, int2* __restrict__ epair)
{
    int e = blockIdx.x * 256 + threadIdx.x;
    if (e >= NE) return;
    int d = ei[NE + e];
    int pos = offs[d] + atomicAdd(&cur[d], 1);
    epair[pos] = make_int2(e, ei[e]);
}

// ---------------- layer1: fused conv1 (MFMA 32x32x16) + segmented reduce ------
// Block = 128 positions. No table staging (global, L1/L2-hot); msg padded [128][33].
__global__ __launch_bounds__(256) void k_layer1(
    const float* __restrict__ x, const float* __restrict__ ea,
    const int2* __restrict__ epair, const int* __restrict__ offs,
    const float* __restrict__ w1, const float* __restrict__ b1,
    const unsigned* __restrict__ bfrag,
    const float* __restrict__ root, const float* __restrict__ bias,
    float* __restrict__ h1, float* __restrict__ agg1)
{
    __shared__ float s_msg[128*33];        // 16896 B, pad-33 (2-way max on writes)
    __shared__ float s_r[512];             // root [16][32]
    __shared__ float s_bias[32];
    __shared__ int   s_nlo, s_nhi;
    const int tid  = threadIdx.x;
    const uint4* bf4 = (const uint4*)bfrag;
    for (int i = tid; i < 512; i += 256) s_r[i] = root[i];
    if (tid < 32) s_bias[tid] = bias[tid];
    const int P0 = blockIdx.x * 128;
    if (tid == 0) {
        int lo = 0, hi = NN;
        while (lo < hi) { int mid = (lo+hi)>>1; if (offs[mid+1] <= P0) lo = mid+1; else hi = mid; }
        s_nlo = lo;
        lo = 0; hi = NN;
        int PL = P0 + 127;
        while (lo < hi) { int mid = (lo+hi)>>1; if (offs[mid+1] <= PL) lo = mid+1; else hi = mid; }
        s_nhi = lo;
    }

    // ---- phase 1: conv into LDS ----
    {
        const int lane = tid & 63;
        const int wid  = tid >> 6;
        const int m    = lane & 31;
        const int g    = lane >> 5;
        const int p    = P0 + wid*32 + m;
        const int2 ep  = epair[p];
        const int e    = ep.x, src = ep.y;

        float xs[8];
        {
            const float4* xp = (const float4*)(x + (size_t)src*16 + g*8);
            float4 aa = xp[0], bb = xp[1];
            xs[0]=aa.x; xs[1]=aa.y; xs[2]=aa.z; xs[3]=aa.w;
            xs[4]=bb.x; xs[5]=bb.y; xs[6]=bb.z; xs[7]=bb.w;
        }
        float h[17];
        {
            const float2 e01 = *(const float2*)(ea + (size_t)e*6);
            const float2 e23 = *(const float2*)(ea + (size_t)e*6 + 2);
            const float2 e45 = *(const float2*)(ea + (size_t)e*6 + 4);
            const float a0=e01.x, a1=e01.y, a2=e23.x, a3=e23.y, a4=e45.x, a5=e45.y;
#pragma unroll
            for (int j = 0; j < 16; ++j) {
                float c = b1[j];
                c += a0*w1[0*16+j]; c += a1*w1[1*16+j]; c += a2*w1[2*16+j];
                c += a3*w1[3*16+j]; c += a4*w1[4*16+j]; c += a5*w1[5*16+j];
                h[j] = fmaxf(c, 0.f);
            }
            h[16] = 1.f;
        }

        f32x16 acc0 = {}, acc1 = {};
#pragma unroll
        for (int s = 0; s < 17; ++s) {
            const float hs = h[s];
            float p0 = hs*xs[0], p1 = hs*xs[1], p2 = hs*xs[2], p3 = hs*xs[3];
            float p4 = hs*xs[4], p5 = hs*xs[5], p6 = hs*xs[6], p7 = hs*xs[7];
            uint4 uh = { pack2(p0,p1), pack2(p2,p3), pack2(p4,p5), pack2(p6,p7) };
            uint4 ul = { pack2(lof(p0),lof(p1)), pack2(lof(p2),lof(p3)),
                         pack2(lof(p4),lof(p5)), pack2(lof(p6),lof(p7)) };
            uint4 wh = bf4[(s*2+0)*64 + lane];
            uint4 wl = bf4[(s*2+1)*64 + lane];
            if (s & 1) {
                acc1 = __builtin_amdgcn_mfma_f32_32x32x16_bf16(asb(uh), asb(wh), acc1, 0, 0, 0);
                acc1 = __builtin_amdgcn_mfma_f32_32x32x16_bf16(asb(uh), asb(wl), acc1, 0, 0, 0);
                acc1 = __builtin_amdgcn_mfma_f32_32x32x16_bf16(asb(ul), asb(wh), acc1, 0, 0, 0);
            } else {
                acc0 = __builtin_amdgcn_mfma_f32_32x32x16_bf16(asb(uh), asb(wh), acc0, 0, 0, 0);
                acc0 = __builtin_amdgcn_mfma_f32_32x32x16_bf16(asb(uh), asb(wl), acc0, 0, 0, 0);
                acc0 = __builtin_amdgcn_mfma_f32_32x32x16_bf16(asb(ul), asb(wh), acc0, 0, 0, 0);
            }
        }
        float* mbase = s_msg + (size_t)wid*32*33;
        const int rb = g*4;
#pragma unroll
        for (int r = 0; r < 16; ++r) {
            int mr = (r&3) + 8*(r>>2) + rb;            // edge-in-tile
            mbase[mr*33 + m] = acc0[r] + acc1[r];      // col = out channel
        }
    }
    __syncthreads();

    // ---- phase 2: segmented reduce + epilogue ----
    {
        const int nlo = s_nlo, nhi = s_nhi;
        const int items = (nhi - nlo + 1) * 8;
        const float4* s_r4 = (const float4*)s_r;
        for (int it = tid; it < items; it += 256) {
            const int n = nlo + (it >> 3);
            const int q = it & 7;
            const int os = offs[n], oe = offs[n+1];
            const int ss = os > P0 ? os : P0;
            const int se = oe < P0+128 ? oe : P0+128;
            if (ss >= se) continue;
            float4 acc = make_float4(0.f, 0.f, 0.f, 0.f);
            for (int p = ss; p < se; ++p) {
                const float* mr = s_msg + (p - P0)*33 + q*4;
                acc.x += mr[0]; acc.y += mr[1]; acc.z += mr[2]; acc.w += mr[3];
            }
            const bool interior = (os >= P0) && (oe <= P0 + 128);
            if (interior) {
                acc.x += s_bias[4*q]; acc.y += s_bias[4*q+1];
                acc.z += s_bias[4*q+2]; acc.w += s_bias[4*q+3];
                const float4* xp4 = (const float4*)(x + (size_t)n * 16);
#pragma unroll
                for (int ii = 0; ii < 4; ++ii) {
                    float4 xv = xp4[ii];
                    float4 w0 = s_r4[(ii*4+0)*8 + q];
                    float4 w1v = s_r4[(ii*4+1)*8 + q];
                    float4 w2v = s_r4[(ii*4+2)*8 + q];
                    float4 w3 = s_r4[(ii*4+3)*8 + q];
                    acc.x += xv.x*w0.x + xv.y*w1v.x + xv.z*w2v.x + xv.w*w3.x;
                    acc.y += xv.x*w0.y + xv.y*w1v.y + xv.z*w2v.y + xv.w*w3.y;
                    acc.z += xv.x*w0.z + xv.y*w1v.z + xv.z*w2v.z + xv.w*w3.z;
                    acc.w += xv.x*w0.w + xv.y*w1v.w + xv.z*w2v.w + xv.w*w3.w;
                }
                acc.x = fmaxf(acc.x, 0.f); acc.y = fmaxf(acc.y, 0.f);
                acc.z = fmaxf(acc.z, 0.f); acc.w = fmaxf(acc.w, 0.f);
                ((float4*)(h1 + (size_t)n * 32))[q] = acc;
            } else {
                float* ap = agg1 + (size_t)n * 32 + q*4;
                atomicAdd(ap + 0, acc.x);
                atomicAdd(ap + 1, acc.y);
                atomicAdd(ap + 2, acc.z);
                atomicAdd(ap + 3, acc.w);
            }
        }
    }
}

// ---------------- fix1: finalize border + zero-degree nodes -------------------
__global__ __launch_bounds__(256) void k_fix1(
    const int* __restrict__ offs, const float* __restrict__ agg1,
    const float* __restrict__ x, const float* __restrict__ root,
    const float* __restrict__ bias, float* __restrict__ h1)
{
    __shared__ float s_r[512];
    __shared__ float s_b[32];
    int tid = threadIdx.x;
    for (int i = tid; i < 512; i += 256) s_r[i] = root[i];
    if (tid < 32) s_b[tid] = bias[tid];
    __syncthreads();
    int gid = blockIdx.x * 256 + tid;
    int n = gid >> 3, q = gid & 7;
    int os = offs[n], oe = offs[n+1];
    bool interior = (oe > os) && ((os >> 7) == ((oe - 1) >> 7));
    if (interior) return;
    float4 acc = ((const float4*)(agg1 + (size_t)n * 32))[q];
    acc.x += s_b[4*q]; acc.y += s_b[4*q+1]; acc.z += s_b[4*q+2]; acc.w += s_b[4*q+3];
    const float4* s_r4 = (const float4*)s_r;
    const float4* xp4 = (const float4*)(x + (size_t)n * 16);
#pragma unroll
    for (int ii = 0; ii < 4; ++ii) {
        float4 xv = xp4[ii];
        float4 w0 = s_r4[(ii*4+0)*8 + q];
        float4 w1v = s_r4[(ii*4+1)*8 + q];
        float4 w2v = s_r4[(ii*4+2)*8 + q];
        float4 w3 = s_r4[(ii*4+3)*8 + q];
        acc.x += xv.x*w0.x + xv.y*w1v.x + xv.z*w2v.x + xv.w*w3.x;
        acc.y += xv.x*w0.y + xv.y*w1v.y + xv.z*w2v.y + xv.w*w3.y;
        acc.z += xv.x*w0.z + xv.y*w1v.z + xv.z*w2v.z + xv.w*w3.z;
        acc.w += xv.x*w0.w + xv.y*w1v.w + xv.z*w2v.w + xv.w*w3.w;
    }
    acc.x = fmaxf(acc.x, 0.f); acc.y = fmaxf(acc.y, 0.f);
    acc.z = fmaxf(acc.z, 0.f); acc.w = fmaxf(acc.w, 0.f);
    ((float4*)(h1 + (size_t)n * 32))[q] = acc;
}

// ---------------- layer2: fused conv2 (h-hoisted 16x16x32) + seg reduce -------
// Block = 64 positions. No table staging; msg padded [64][17].
__global__ __launch_bounds__(256) void k_layer2(
    const float* __restrict__ x, const float* __restrict__ ea,
    const int2* __restrict__ epair, const int* __restrict__ offs,
    const float* __restrict__ w1, const float* __restrict__ b1,
    const unsigned* __restrict__ bfrag,
    const float* __restrict__ root, const float* __restrict__ bias,
    float* __restrict__ h2, float* __restrict__ agg2)
{
    __shared__ float s_msg[64*17];         // 4352 B, pad-17
    __shared__ float s_r[512];             // root [32][16]
    __shared__ float s_bias[16];
    __shared__ int   s_nlo, s_nhi;
    const int tid  = threadIdx.x;
    const uint4* bf4 = (const uint4*)bfrag;
    for (int i = tid; i < 512; i += 256) s_r[i] = root[i];
    if (tid < 16) s_bias[tid] = bias[tid];
    const int P0 = blockIdx.x * 64;
    if (tid == 0) {
        int lo = 0, hi = NN;
        while (lo < hi) { int mid = (lo+hi)>>1; if (offs[mid+1] <= P0) lo = mid+1; else hi = mid; }
        s_nlo = lo;
        lo = 0; hi = NN;
        int PL = P0 + 63;
        while (lo < hi) { int mid = (lo+hi)>>1; if (offs[mid+1] <= PL) lo = mid+1; else hi = mid; }
        s_nhi = lo;
    }

    // ---- phase 1: conv into LDS ----
    {
        const int lane = tid & 63;
        const int wid  = tid >> 6;
        const int m    = lane & 15;
        const int g    = lane >> 4;
        const int p    = P0 + wid*16 + m;
        const int2 ep  = epair[p];
        const int e    = ep.x, src = ep.y;

        uint4 xh, xl;
        {
            const float4* xp = (const float4*)(x + (size_t)src*32 + g*8);
            float4 aa = xp[0], bb = xp[1];
            xh = (uint4){ pack2(aa.x,aa.y), pack2(aa.z,aa.w), pack2(bb.x,bb.y), pack2(bb.z,bb.w) };
            xl = (uint4){ pack2(lof(aa.x),lof(aa.y)), pack2(lof(aa.z),lof(aa.w)),
                          pack2(lof(bb.x),lof(bb.y)), pack2(lof(bb.z),lof(bb.w)) };
        }
        float h[17];
        {
            const float2 e01 = *(const float2*)(ea + (size_t)e*6);
            const float2 e23 = *(const float2*)(ea + (size_t)e*6 + 2);
            const float2 e45 = *(const float2*)(ea + (size_t)e*6 + 4);
            const float a0=e01.x, a1=e01.y, a2=e23.x, a3=e23.y, a4=e45.x, a5=e45.y;
#pragma unroll
            for (int j = 0; j < 16; ++j) {
                float c = b1[j];
                c += a0*w1[0*16+j]; c += a1*w1[1*16+j]; c += a2*w1[2*16+j];
                c += a3*w1[3*16+j]; c += a4*w1[4*16+j]; c += a5*w1[5*16+j];
                h[j] = fmaxf(c, 0.f);
            }
            h[16] = 1.f;
        }

        f32x4 macc = {};
#pragma unroll
        for (int s = 0; s < 17; ++s) {
            uint4 wh = bf4[(s*2+0)*64 + lane];
            uint4 wl = bf4[(s*2+1)*64 + lane];
            f32x4 t = {};
            t = __builtin_amdgcn_mfma_f32_16x16x32_bf16(asb(wh), asb(xh), t, 0, 0, 0);
            t = __builtin_amdgcn_mfma_f32_16x16x32_bf16(asb(wl), asb(xh), t, 0, 0, 0);
            t = __builtin_amdgcn_mfma_f32_16x16x32_bf16(asb(wh), asb(xl), t, 0, 0, 0);
            const float hs = h[s];
            macc.x += hs*t.x; macc.y += hs*t.y; macc.z += hs*t.z; macc.w += hs*t.w;
        }
        // D row o = g*4+r, col edge m -> LDS [edge][o], pad 17
        float* lw = s_msg + (wid*16 + m)*17 + g*4;
        lw[0] = macc.x;
        lw[1] = macc.y;
        lw[2] = macc.z;
        lw[3] = macc.w;
    }
    __syncthreads();

    // ---- phase 2: segmented reduce + epilogue ----
    {
        const int nlo = s_nlo, nhi = s_nhi;
        const int items = (nhi - nlo + 1) * 4;
        const float4* s_r4 = (const float4*)s_r;
        for (int it = tid; it < items; it += 256) {
            const int n = nlo + (it >> 2);
            const int q = it & 3;
            const int os = offs[n], oe = offs[n+1];
            const int ss = os > P0 ? os : P0;
            const int se = oe < P0+64 ? oe : P0+64;
            if (ss >= se) continue;
            float4 acc = make_float4(0.f, 0.f, 0.f, 0.f);
            for (int p = ss; p < se; ++p) {
                const float* mr = s_msg + (p - P0)*17 + q*4;
                acc.x += mr[0]; acc.y += mr[1]; acc.z += mr[2]; acc.w += mr[3];
            }
            const bool interior = (os >= P0) && (oe <= P0 + 64);
            if (interior) {
                acc.x += s_bias[4*q]; acc.y += s_bias[4*q+1];
                acc.z += s_bias[4*q+2]; acc.w += s_bias[4*q+3];
                const float4* xp4 = (const float4*)(x + (size_t)n * 32);
#pragma unroll
                for (int ii = 0; ii < 8; ++ii) {
                    float4 xv = xp4[ii];
                    float4 w0 = s_r4[(ii*4+0)*4 + q];
                    float4 w1v = s_r4[(ii*4+1)*4 + q];
                    float4 w2v = s_r4[(ii*4+2)*4 + q];
                    float4 w3 = s_r4[(ii*4+3)*4 + q];
                    acc.x += xv.x*w0.x + xv.y*w1v.x + xv.z*w2v.x + xv.w*w3.x;
                    acc.y += xv.x*w0.y + xv.y*w1v.y + xv.z*w2v.y + xv.w*w3.y;
                    acc.z += xv.x*w0.z + xv.y*w1v.z + xv.z*w2v.z + xv.w*w3.z;
                    acc.w += xv.x*w0.w + xv.y*w1v.w + xv.z*w2v.w + xv.w*w3.w;
                }
                acc.x = fmaxf(acc.x, 0.f); acc.y = fmaxf(acc.y, 0.f);
                acc.z = fmaxf(acc.z, 0.f); acc.w = fmaxf(acc.w, 0.f);
                ((float4*)(h2 + (size_t)n * 16))[q] = acc;
            } else {
                float* ap = agg2 + (size_t)n * 16 + q*4;
                atomicAdd(ap + 0, acc.x);
                atomicAdd(ap + 1, acc.y);
                atomicAdd(ap + 2, acc.z);
                atomicAdd(ap + 3, acc.w);
            }
        }
    }
}

// ---------------- fix2: finalize border + zero-degree nodes -------------------
__global__ __launch_bounds__(256) void k_fix2(
    const int* __restrict__ offs, const float* __restrict__ agg2,
    const float* __restrict__ h1, const float* __restrict__ root,
    const float* __restrict__ bias, float* __restrict__ h2)
{
    __shared__ float s_r[512];
    __shared__ float s_b[16];
    int tid = threadIdx.x;
    for (int i = tid; i < 512; i += 256) s_r[i] = root[i];
    if (tid < 16) s_b[tid] = bias[tid];
    __syncthreads();
    int gid = blockIdx.x * 256 + tid;
    int n = gid >> 2, q = gid & 3;
    int os = offs[n], oe = offs[n+1];
    bool interior = (oe > os) && ((os >> 6) == ((oe - 1) >> 6));
    if (interior) return;
    float4 acc = ((const float4*)(agg2 + (size_t)n * 16))[q];
    acc.x += s_b[4*q]; acc.y += s_b[4*q+1]; acc.z += s_b[4*q+2]; acc.w += s_b[4*q+3];
    const float4* s_r4 = (const float4*)s_r;
    const float4* xp4 = (const float4*)(h1 + (size_t)n * 32);
#pragma unroll
    for (int ii = 0; ii < 8; ++ii) {
        float4 xv = xp4[ii];
        float4 w0 = s_r4[(ii*4+0)*4 + q];
        float4 w1v = s_r4[(ii*4+1)*4 + q];
        float4 w2v = s_r4[(ii*4+2)*4 + q];
        float4 w3 = s_r4[(ii*4+3)*4 + q];
        acc.x += xv.x*w0.x + xv.y*w1v.x + xv.z*w2v.x + xv.w*w3.x;
        acc.y += xv.x*w0.y + xv.y*w1v.y + xv.z*w2v.y + xv.w*w3.y;
        acc.z += xv.x*w0.z + xv.y*w1v.z + xv.z*w2v.z + xv.w*w3.z;
        acc.w += xv.x*w0.w + xv.y*w1v.w + xv.z*w2v.w + xv.w*w3.w;
    }
    acc.x = fmaxf(acc.x, 0.f); acc.y = fmaxf(acc.y, 0.f);
    acc.z = fmaxf(acc.z, 0.f); acc.w = fmaxf(acc.w, 0.f);
    ((float4*)(h2 + (size_t)n * 16))[q] = acc;
}

// ---------------- mean pool + concat + head ----------------------------------
__global__ __launch_bounds__(64) void k_head(
    const float* __restrict__ h2, const float* __restrict__ x_att,
    const int* __restrict__ goffs,
    const float* __restrict__ l1w, const float* __restrict__ l1b,
    const float* __restrict__ l2w, const float* __restrict__ l2b,
    float* __restrict__ out)
{
    int g = blockIdx.x;
    int lane = threadIdx.x;
    int s = goffs[g], e = goffs[g + 1];
    __shared__ float v[32];
    __shared__ float hmid[8];
    int f = lane & 15, sub = lane >> 4;
    float acc = 0.f;
    for (int i = s + sub; i < e; i += 4) acc += h2[(size_t)i*16 + f];
    acc += __shfl_xor(acc, 16);
    acc += __shfl_xor(acc, 32);
    float cnt = fmaxf((float)(e - s), 1.0f);
    if (lane < 16) {
        v[lane]      = acc / cnt;
        v[16 + lane] = x_att[g*16 + lane];
    }
    __syncthreads();
    if (lane < 8) {
        float a = l1b[lane];
#pragma unroll
        for (int i = 0; i < 32; ++i) a += v[i] * l1w[i*8 + lane];
        hmid[lane] = a;
    }
    __syncthreads();
    if (lane == 0) {
        float a = l2b[0];
#pragma unroll
        for (int j = 0; j < 8; ++j) a += hmid[j] * l2w[j];
        out[g] = a;
    }
}

extern "C" void kernel_launch(void* const* d_in, const int* in_sizes, int n_in,
                              void* d_out, int out_size, void* d_ws, size_t ws_size,
                              hipStream_t stream) {
    const float* x_p    = (const float*)d_in[0];
    const float* ea_p   = (const float*)d_in[2];
    const int*   ei     = (const int*)d_in[4];
    const int*   batch  = (const int*)d_in[5];
    const float* nn1_w1 = (const float*)d_in[6];
    const float* nn1_b1 = (const float*)d_in[7];
    const float* nn1_w2 = (const float*)d_in[8];
    const float* nn1_b2 = (const float*)d_in[9];
    const float* root1  = (const float*)d_in[10];
    const float* bias1  = (const float*)d_in[11];
    const float* nn2_w1 = (const float*)d_in[12];
    const float* nn2_b1 = (const float*)d_in[13];
    const float* nn2_w2 = (const float*)d_in[14];
    const float* nn2_b2 = (const float*)d_in[15];
    const float* root2  = (const float*)d_in[16];
    const float* bias2  = (const float*)d_in[17];
    const float* gw1    = (const float*)d_in[18];
    const float* gb1    = (const float*)d_in[19];
    const float* gw2    = (const float*)d_in[20];
    const float* gb2    = (const float*)d_in[21];
    const float* l1w    = (const float*)d_in[22];
    const float* l1b    = (const float*)d_in[23];
    const float* l2w    = (const float*)d_in[24];
    const float* l2b    = (const float*)d_in[25];

    // -------- workspace layout (~28 MB) --------
    float*    h1     = (float*)d_ws;                     // NN*32
    float*    h2     = h1 + (size_t)NN * 32;             // NN*16
    float*    agg1   = h2 + (size_t)NN * 16;             // NN*32
    float*    agg2   = agg1 + (size_t)NN * 32;           // NN*16
    float*    x_att  = agg2 + (size_t)NN * 16;           // NG*16
    int*      goffs  = (int*)(x_att + (size_t)NG * 16);  // 2052
    int*      offs   = goffs + 2052;                     // 65540
    int*      cnt    = offs + 65540;                     // NN
    int*      cur    = cnt + NN;                         // NN
    int2*     epair  = (int2*)(cur + NN);                // NE int2
    unsigned* bfrag1 = (unsigned*)(epair + NE);          // 8704
    unsigned* bfrag2 = bfrag1 + 8704;                    // 8704

    k_setup<<<512, 256, 0, stream>>>(batch, nn1_w2, nn1_b2, nn2_w2, nn2_b2,
                                     cnt, cur, goffs, agg1, agg2, bfrag1, bfrag2);
    k_gateatt<<<NG, 64, 0, stream>>>(x_p, ei, cnt, gw1, gb1, gw2, gb2, goffs, x_att);
    k_scan<<<1, 1024, 0, stream>>>(cnt, offs);
    k_scatter<<<NE/256, 256, 0, stream>>>(ei, offs, cur, epair);
    k_layer1<<<NE/128, 256, 0, stream>>>(x_p, ea_p, epair, offs,
                                         nn1_w1, nn1_b1, bfrag1, root1, bias1, h1, agg1);
    k_fix1<<<NN*8/256, 256, 0, stream>>>(offs, agg1, x_p, root1, bias1, h1);
    k_layer2<<<NE/64, 256, 0, stream>>>(h1, ea_p, epair, offs,
                                        nn2_w1, nn2_b1, bfrag2, root2, bias2, h2, agg2);
    k_fix2<<<NN*4/256, 256, 0, stream>>>(offs, agg2, h1, root2, bias2, h2);
    k_head<<<NG, 64, 0, stream>>>(h2, x_att, goffs, l1w, l1b, l2w, l2b, (float*)d_out);
}

// Round 17
// 136.226 us; speedup vs baseline: 1.3903x; 1.2712x over previous
//
#include <hip/hip_runtime.h>

#define NN 65536
#define NE 262144
#define NG 2048

typedef __attribute__((ext_vector_type(16))) float f32x16;
typedef __attribute__((ext_vector_type(4)))  float f32x4;
typedef __attribute__((ext_vector_type(8)))  __bf16 bf16x8;

// pack two fp32 -> dword of two bf16 (truncation); low16 = a, high16 = b
__device__ inline unsigned pack2(float a, float b) {
    return __builtin_amdgcn_perm(__float_as_uint(b), __float_as_uint(a), 0x07060302u);
}
// remainder after bf16-truncation (exact in fp32)
__device__ inline float lof(float p) {
    return p - __uint_as_float(__float_as_uint(p) & 0xffff0000u);
}
__device__ inline bf16x8 asb(uint4 u) { return __builtin_bit_cast(bf16x8, u); }
__device__ inline void wave_lds_fence() {
    asm volatile("s_waitcnt lgkmcnt(0)" ::: "memory");
}

// ---------------- setup: zero cnt/cur + goffs + W-fragment prep --------------
__global__ __launch_bounds__(256) void k_setup(
    const int* __restrict__ batch,
    const float* __restrict__ w2a, const float* __restrict__ b2a,
    const float* __restrict__ w2b, const float* __restrict__ b2c,
    int* __restrict__ cnt, int* __restrict__ cur, int* __restrict__ goffs,
    unsigned* __restrict__ f1, unsigned* __restrict__ f2)
{
    int t = blockIdx.x * 256 + threadIdx.x;      // 0..131071
    if (t < NN) { cnt[t] = 0; cur[t] = 0; }
    if (t <= NG) {
        int lo = 0, hi = NN;
        while (lo < hi) {
            int mid = (lo + hi) >> 1;
            if (batch[mid] < t) lo = mid + 1; else hi = mid;
        }
        goffs[t] = lo;
    }
    if (t < 17408) {
        int c = t / 8704;
        int r = t - c * 8704;
        int d = r & 3;
        int l = (r >> 2) & 63;
        int tt = (r >> 8) & 1;
        int s = r >> 9;
        if (c == 0) {   // conv1 table: slot (l>>5)*8+j of K-step s, col o = l&31
            int n = l & 31, g = l >> 5;
            int j0 = 2*d;
            int c0 = (g*8 + j0)*32 + n;
            int c1 = c0 + 32;
            float a = (s < 16) ? w2a[s*512 + c0] : b2a[c0];
            float b = (s < 16) ? w2a[s*512 + c1] : b2a[c1];
            f1[r] = tt ? pack2(lof(a), lof(b)) : pack2(a, b);
        } else {        // conv2 table: slot (l>>4)*8+j of K-step s, row o = l&15
            int n = l & 15, g = l >> 4;
            int j0 = 2*d;
            int c0 = (g*8 + j0)*16 + n;
            int c1 = c0 + 16;
            float a = (s < 16) ? w2b[s*512 + c0] : b2c[c0];
            float b = (s < 16) ? w2b[s*512 + c1] : b2c[c1];
            f2[r] = tt ? pack2(lof(a), lof(b)) : pack2(a, b);
        }
    }
}

// ---------------- fused gate + attention pool (one block per graph) ----------
__global__ __launch_bounds__(64) void k_gateatt(const float* __restrict__ x,
    const float* __restrict__ gw1, const float* __restrict__ gb1,
    const float* __restrict__ gw2, const float* __restrict__ gb2,
    const int* __restrict__ goffs, float* __restrict__ x_att)
{
    __shared__ float sw[256];
    __shared__ float sb[16];
    __shared__ float sw2[16];
    __shared__ float sb2;
    __shared__ float gb[1024];
    const int g = blockIdx.x;
    const int lane = threadIdx.x;
    for (int i = lane; i < 256; i += 64) sw[i] = gw1[i];
    if (lane < 16) { sb[lane] = gb1[lane]; sw2[lane] = gw2[lane]; }
    if (lane == 0) sb2 = gb2[0];
    const int s = goffs[g], e = goffs[g + 1];
    const int cnt = e - s;
    if (cnt <= 0) {
        if (lane < 16) x_att[g*16 + lane] = 0.f;
        return;
    }
    const int cap = cnt < 1024 ? cnt : 1024;
    __syncthreads();
    for (int ii = lane; ii < cap; ii += 64) {
        const float4* xp = (const float4*)(x + (size_t)(s + ii) * 16);
        float xv[16];
#pragma unroll
        for (int i = 0; i < 4; ++i) {
            float4 tt = xp[i];
            xv[4*i] = tt.x; xv[4*i+1] = tt.y; xv[4*i+2] = tt.z; xv[4*i+3] = tt.w;
        }
        float gv = sb2;
#pragma unroll
        for (int j = 0; j < 16; ++j) {
            float a = sb[j];
#pragma unroll
            for (int i = 0; i < 16; ++i) a += xv[i] * sw[i*16 + j];
            gv += fmaxf(a, 0.f) * sw2[j];
        }
        gb[ii] = gv;
    }
    __syncthreads();
    float m = -1e30f;
    for (int ii = lane; ii < cap; ii += 64) m = fmaxf(m, gb[ii]);
#pragma unroll
    for (int d = 32; d; d >>= 1) m = fmaxf(m, __shfl_xor(m, d));
    float sum = 0.f;
    for (int ii = lane; ii < cap; ii += 64) {
        float ev = expf(gb[ii] - m);
        gb[ii] = ev;
        sum += ev;
    }
#pragma unroll
    for (int d = 32; d; d >>= 1) sum += __shfl_xor(sum, d);
    const float inv = 1.f / sum;
    __syncthreads();
    const int f = lane & 15, sub = lane >> 4;
    float acc = 0.f;
    for (int ii = sub; ii < cap; ii += 4)
        acc += gb[ii] * inv * x[(size_t)(s + ii)*16 + f];
    acc += __shfl_xor(acc, 16);
    acc += __shfl_xor(acc, 32);
    if (lane < 16) x_att[g*16 + f] = acc;
}

// ---------------- CSR build: histogram / scan / scatter ----------------------
__global__ __launch_bounds__(256) void k_hist(const int* __restrict__ ei, int* __restrict__ cnt)
{
    int e = blockIdx.x * 256 + threadIdx.x;
    if (e >= NE) return;
    atomicAdd(&cnt[ei[NE + e]], 1);
}

__global__ __launch_bounds__(256) void k_scan_blk(const int* __restrict__ cnt,
    int* __restrict__ offs, int* __restrict__ bsum)
{
    __shared__ int s[256];
    int t = threadIdx.x, b = blockIdx.x;
    int v = cnt[b*256 + t];
    s[t] = v;
    __syncthreads();
#pragma unroll
    for (int d = 1; d < 256; d <<= 1) {
        int add = (t >= d) ? s[t - d] : 0;
        __syncthreads();
        s[t] += add;
        __syncthreads();
    }
    offs[b*256 + t] = s[t] - v;
    if (t == 255) bsum[b] = s[255];
}

__global__ __launch_bounds__(256) void k_scan_top(const int* __restrict__ bsum,
    int* __restrict__ boff)
{
    __shared__ int s[256];
    int t = threadIdx.x;
    int v = bsum[t];
    s[t] = v;
    __syncthreads();
#pragma unroll
    for (int d = 1; d < 256; d <<= 1) {
        int add = (t >= d) ? s[t - d] : 0;
        __syncthreads();
        s[t] += add;
        __syncthreads();
    }
    boff[t] = s[t] - v;
}

__global__ __launch_bounds__(256) void k_scan_add(int* __restrict__ offs,
    const int* __restrict__ boff)
{
    int i = blockIdx.x * 256 + threadIdx.x;
    if (i == 0) offs[NN] = NE;
    if (i >= NN) return;
    offs[i] += boff[i >> 8];
}

__global__ __launch_bounds__(256) void k_scatter(const int* __restrict__ ei,
    const int* __restrict__ offs, int* __restrict__ cur, int2* __restrict__ epair)
{
    int e = blockIdx.x * 256 + threadIdx.x;
    if (e >= NE) return;
    int d = ei[NE + e];
    int pos = offs[d] + atomicAdd(&cur[d], 1);
    epair[pos] = make_int2(e, ei[e]);
}

// ---------------- conv1: NNConv(16->32) via MFMA 32x32x16 --------------------
// Dual-acc form (A = u = h*x split-bf16, B = W table), W table staged in LDS.
__global__ __launch_bounds__(256) void k_conv1(
    const float* __restrict__ x, const float* __restrict__ ea,
    const int2* __restrict__ epair,
    const float* __restrict__ w1, const float* __restrict__ b1,
    const unsigned* __restrict__ bfrag, float* __restrict__ msg)
{
    __shared__ uint4 s_tab[17*2*64];
    const int tid  = threadIdx.x;
    for (int i = tid; i < 17*2*64; i += 256) s_tab[i] = ((const uint4*)bfrag)[i];
    __syncthreads();
    const int lane = tid & 63;
    const int wid  = tid >> 6;
    const int m    = lane & 31;     // edge in tile; for D: col = out channel
    const int g    = lane >> 5;     // k-group

    const int tile = blockIdx.x*4 + wid;
    const int p    = tile*32 + m;
    const int2 ep  = epair[p];
    const int e    = ep.x, src = ep.y;

    float xs[8];
    {
        const float4* xp = (const float4*)(x + (size_t)src*16 + g*8);
        float4 aa = xp[0], bb = xp[1];
        xs[0]=aa.x; xs[1]=aa.y; xs[2]=aa.z; xs[3]=aa.w;
        xs[4]=bb.x; xs[5]=bb.y; xs[6]=bb.z; xs[7]=bb.w;
    }
    float h[17];
    {
        const float2 e01 = *(const float2*)(ea + (size_t)e*6);
        const float2 e23 = *(const float2*)(ea + (size_t)e*6 + 2);
        const float2 e45 = *(const float2*)(ea + (size_t)e*6 + 4);
        const float a0=e01.x, a1=e01.y, a2=e23.x, a3=e23.y, a4=e45.x, a5=e45.y;
#pragma unroll
        for (int j = 0; j < 16; ++j) {
            float c = b1[j];
            c += a0*w1[0*16+j]; c += a1*w1[1*16+j]; c += a2*w1[2*16+j];
            c += a3*w1[3*16+j]; c += a4*w1[4*16+j]; c += a5*w1[5*16+j];
            h[j] = fmaxf(c, 0.f);
        }
        h[16] = 1.f;
    }

    f32x16 acc0 = {}, acc1 = {};
#pragma unroll
    for (int s = 0; s < 17; ++s) {
        const float hs = h[s];
        float p0 = hs*xs[0], p1 = hs*xs[1], p2 = hs*xs[2], p3 = hs*xs[3];
        float p4 = hs*xs[4], p5 = hs*xs[5], p6 = hs*xs[6], p7 = hs*xs[7];
        uint4 uh = { pack2(p0,p1), pack2(p2,p3), pack2(p4,p5), pack2(p6,p7) };
        uint4 ul = { pack2(lof(p0),lof(p1)), pack2(lof(p2),lof(p3)),
                     pack2(lof(p4),lof(p5)), pack2(lof(p6),lof(p7)) };
        uint4 wh = s_tab[(s*2+0)*64 + lane];
        uint4 wl = s_tab[(s*2+1)*64 + lane];
        if (s & 1) {
            acc1 = __builtin_amdgcn_mfma_f32_32x32x16_bf16(asb(uh), asb(wh), acc1, 0, 0, 0);
            acc1 = __builtin_amdgcn_mfma_f32_32x32x16_bf16(asb(uh), asb(wl), acc1, 0, 0, 0);
            acc1 = __builtin_amdgcn_mfma_f32_32x32x16_bf16(asb(ul), asb(wh), acc1, 0, 0, 0);
        } else {
            acc0 = __builtin_amdgcn_mfma_f32_32x32x16_bf16(asb(uh), asb(wh), acc0, 0, 0, 0);
            acc0 = __builtin_amdgcn_mfma_f32_32x32x16_bf16(asb(uh), asb(wl), acc0, 0, 0, 0);
            acc0 = __builtin_amdgcn_mfma_f32_32x32x16_bf16(asb(ul), asb(wh), acc0, 0, 0, 0);
        }
    }

    float* mbase = msg + (size_t)tile*32*32;
    const int rb = g*4;
#pragma unroll
    for (int r = 0; r < 16; ++r) {
        int mr = (r&3) + 8*(r>>2) + rb;               // D row = edge-in-tile
        mbase[(size_t)mr*32 + m] = acc0[r] + acc1[r]; // D col (lane&31) = out channel
    }
}

// ---------------- conv2: NNConv(32->16), h-hoisted MFMA 16x16x32 -------------
__global__ __launch_bounds__(256) void k_conv2(
    const float* __restrict__ x, const float* __restrict__ ea,
    const int2* __restrict__ epair,
    const float* __restrict__ w1, const float* __restrict__ b1,
    const unsigned* __restrict__ bfrag, float* __restrict__ msg)
{
    __shared__ uint4 s_tab[17*2*64];
    __shared__ float lt[4][16*21];
    const int tid  = threadIdx.x;
    for (int i = tid; i < 17*2*64; i += 256) s_tab[i] = ((const uint4*)bfrag)[i];
    __syncthreads();
    const int lane = tid & 63;
    const int wid  = tid >> 6;
    const int m    = lane & 15;     // B col = edge in tile
    const int g    = lane >> 4;     // 8-slot group (i-range g*8..g*8+7)

    const int tile = blockIdx.x*4 + wid;
    const int p    = tile*16 + m;
    const int2 ep  = epair[p];
    const int e    = ep.x, src = ep.y;

    uint4 xh, xl;
    {
        const float4* xp = (const float4*)(x + (size_t)src*32 + g*8);
        float4 aa = xp[0], bb = xp[1];
        xh = (uint4){ pack2(aa.x,aa.y), pack2(aa.z,aa.w), pack2(bb.x,bb.y), pack2(bb.z,bb.w) };
        xl = (uint4){ pack2(lof(aa.x),lof(aa.y)), pack2(lof(aa.z),lof(aa.w)),
                      pack2(lof(bb.x),lof(bb.y)), pack2(lof(bb.z),lof(bb.w)) };
    }
    float h[17];
    {
        const float2 e01 = *(const float2*)(ea + (size_t)e*6);
        const float2 e23 = *(const float2*)(ea + (size_t)e*6 + 2);
        const float2 e45 = *(const float2*)(ea + (size_t)e*6 + 4);
        const float a0=e01.x, a1=e01.y, a2=e23.x, a3=e23.y, a4=e45.x, a5=e45.y;
#pragma unroll
        for (int j = 0; j < 16; ++j) {
            float c = b1[j];
            c += a0*w1[0*16+j]; c += a1*w1[1*16+j]; c += a2*w1[2*16+j];
            c += a3*w1[3*16+j]; c += a4*w1[4*16+j]; c += a5*w1[5*16+j];
            h[j] = fmaxf(c, 0.f);
        }
        h[16] = 1.f;
    }

    f32x4 macc = {};
#pragma unroll
    for (int s = 0; s < 17; ++s) {
        uint4 wh = s_tab[(s*2+0)*64 + lane];
        uint4 wl = s_tab[(s*2+1)*64 + lane];
        f32x4 t = {};
        t = __builtin_amdgcn_mfma_f32_16x16x32_bf16(asb(wh), asb(xh), t, 0, 0, 0);
        t = __builtin_amdgcn_mfma_f32_16x16x32_bf16(asb(wl), asb(xh), t, 0, 0, 0);
        t = __builtin_amdgcn_mfma_f32_16x16x32_bf16(asb(wh), asb(xl), t, 0, 0, 0);
        const float hs = h[s];
        macc.x += hs*t.x; macc.y += hs*t.y; macc.z += hs*t.z; macc.w += hs*t.w;
    }

    // D: row o = g*4+r, col edge = m. Transpose via LDS [edge][o] pad 21.
    float* lw = lt[wid];
    lw[m*21 + g*4 + 0] = macc.x;
    lw[m*21 + g*4 + 1] = macc.y;
    lw[m*21 + g*4 + 2] = macc.z;
    lw[m*21 + g*4 + 3] = macc.w;
    wave_lds_fence();
    const int rrow = lane >> 2, fq = lane & 3;       // 16 rows x 4 float4
    float o0 = lw[rrow*21 + fq*4 + 0];
    float o1 = lw[rrow*21 + fq*4 + 1];
    float o2 = lw[rrow*21 + fq*4 + 2];
    float o3 = lw[rrow*21 + fq*4 + 3];
    float4* mb = (float4*)(msg + (size_t)tile*256);
    mb[rrow*4 + fq] = make_float4(o0, o1, o2, o3);
}

// ---------------- reduce1: h1 = relu(segsum(msg) + x@root1 + bias1) ----------
__global__ __launch_bounds__(256) void k_reduce1(
    const float* __restrict__ msg, const int* __restrict__ offs,
    const float* __restrict__ x, const float* __restrict__ root,
    const float* __restrict__ bias, float* __restrict__ h1)
{
    __shared__ float s_r[512];   // [16][32]
    __shared__ float s_b[32];
    int tid = threadIdx.x;
    for (int i = tid; i < 512; i += 256) s_r[i] = root[i];
    if (tid < 32) s_b[tid] = bias[tid];
    __syncthreads();
    int gid = blockIdx.x * 256 + tid;
    int n = gid >> 3, q = gid & 7;
    int s = offs[n], e = offs[n + 1];
    float4 acc = make_float4(s_b[4*q], s_b[4*q+1], s_b[4*q+2], s_b[4*q+3]);
    const float4* s_r4 = (const float4*)s_r;
    const float* xp = x + (size_t)n * 16;
#pragma unroll
    for (int i = 0; i < 16; ++i) {
        float xi = xp[i];
        float4 w = s_r4[i*8 + q];
        acc.x += xi*w.x; acc.y += xi*w.y; acc.z += xi*w.z; acc.w += xi*w.w;
    }
    for (int p = s; p < e; ++p) {
        float4 mr = ((const float4*)(msg + (size_t)p * 32))[q];
        acc.x += mr.x; acc.y += mr.y; acc.z += mr.z; acc.w += mr.w;
    }
    acc.x = fmaxf(acc.x, 0.f); acc.y = fmaxf(acc.y, 0.f);
    acc.z = fmaxf(acc.z, 0.f); acc.w = fmaxf(acc.w, 0.f);
    ((float4*)(h1 + (size_t)n * 32))[q] = acc;
}

// ---------------- reduce2: h2 = relu(segsum(msg) + h1@root2 + bias2) ---------
__global__ __launch_bounds__(256) void k_reduce2(
    const float* __restrict__ msg, const int* __restrict__ offs,
    const float* __restrict__ h1, const float* __restrict__ root,
    const float* __restrict__ bias, float* __restrict__ h2)
{
    __shared__ float s_r[512];   // [32][16]
    __shared__ float s_b[16];
    int tid = threadIdx.x;
    for (int i = tid; i < 512; i += 256) s_r[i] = root[i];
    if (tid < 16) s_b[tid] = bias[tid];
    __syncthreads();
    int gid = blockIdx.x * 256 + tid;
    int n = gid >> 2, q = gid & 3;
    int s = offs[n], e = offs[n + 1];
    float4 acc = make_float4(s_b[4*q], s_b[4*q+1], s_b[4*q+2], s_b[4*q+3]);
    const float4* s_r4 = (const float4*)s_r;
    const float* xp = h1 + (size_t)n * 32;
#pragma unroll
    for (int i = 0; i < 32; ++i) {
        float xi = xp[i];
        float4 w = s_r4[i*4 + q];
        acc.x += xi*w.x; acc.y += xi*w.y; acc.z += xi*w.z; acc.w += xi*w.w;
    }
    for (int p = s; p < e; ++p) {
        float4 mr = ((const float4*)(msg + (size_t)p * 16))[q];
        acc.x += mr.x; acc.y += mr.y; acc.z += mr.z; acc.w += mr.w;
    }
    acc.x = fmaxf(acc.x, 0.f); acc.y = fmaxf(acc.y, 0.f);
    acc.z = fmaxf(acc.z, 0.f); acc.w = fmaxf(acc.w, 0.f);
    ((float4*)(h2 + (size_t)n * 16))[q] = acc;
}

// ---------------- mean pool + concat + head ----------------------------------
__global__ __launch_bounds__(64) void k_head(
    const float* __restrict__ h2, const float* __restrict__ x_att,
    const int* __restrict__ goffs,
    const float* __restrict__ l1w, const float* __restrict__ l1b,
    const float* __restrict__ l2w, const float* __restrict__ l2b,
    float* __restrict__ out)
{
    int g = blockIdx.x;
    int lane = threadIdx.x;
    int s = goffs[g], e = goffs[g + 1];
    __shared__ float v[32];
    __shared__ float hmid[8];
    int f = lane & 15, sub = lane >> 4;
    float acc = 0.f;
    for (int i = s + sub; i < e; i += 4) acc += h2[(size_t)i*16 + f];
    acc += __shfl_xor(acc, 16);
    acc += __shfl_xor(acc, 32);
    float cnt = fmaxf((float)(e - s), 1.0f);
    if (lane < 16) {
        v[lane]      = acc / cnt;
        v[16 + lane] = x_att[g*16 + lane];
    }
    __syncthreads();
    if (lane < 8) {
        float a = l1b[lane];
#pragma unroll
        for (int i = 0; i < 32; ++i) a += v[i] * l1w[i*8 + lane];
        hmid[lane] = a;
    }
    __syncthreads();
    if (lane == 0) {
        float a = l2b[0];
#pragma unroll
        for (int j = 0; j < 8; ++j) a += hmid[j] * l2w[j];
        out[g] = a;
    }
}

extern "C" void kernel_launch(void* const* d_in, const int* in_sizes, int n_in,
                              void* d_out, int out_size, void* d_ws, size_t ws_size,
                              hipStream_t stream) {
    const float* x_p    = (const float*)d_in[0];
    const float* ea_p   = (const float*)d_in[2];
    const int*   ei     = (const int*)d_in[4];
    const int*   batch  = (const int*)d_in[5];
    const float* nn1_w1 = (const float*)d_in[6];
    const float* nn1_b1 = (const float*)d_in[7];
    const float* nn1_w2 = (const float*)d_in[8];
    const float* nn1_b2 = (const float*)d_in[9];
    const float* root1  = (const float*)d_in[10];
    const float* bias1  = (const float*)d_in[11];
    const float* nn2_w1 = (const float*)d_in[12];
    const float* nn2_b1 = (const float*)d_in[13];
    const float* nn2_w2 = (const float*)d_in[14];
    const float* nn2_b2 = (const float*)d_in[15];
    const float* root2  = (const float*)d_in[16];
    const float* bias2  = (const float*)d_in[17];
    const float* gw1    = (const float*)d_in[18];
    const float* gb1    = (const float*)d_in[19];
    const float* gw2    = (const float*)d_in[20];
    const float* gb2    = (const float*)d_in[21];
    const float* l1w    = (const float*)d_in[22];
    const float* l1b    = (const float*)d_in[23];
    const float* l2w    = (const float*)d_in[24];
    const float* l2b    = (const float*)d_in[25];

    // -------- workspace layout --------
    float*    h1     = (float*)d_ws;                     // NN*32
    float*    h2     = h1 + (size_t)NN * 32;             // NN*16
    float*    x_att  = h2 + (size_t)NN * 16;             // NG*16
    int*      goffs  = (int*)(x_att + (size_t)NG * 16);  // 2052
    int*      offs   = goffs + 2052;                     // 65540
    int*      cnt    = offs + 65540;                     // NN
    int*      cur    = cnt + NN;                         // NN
    int*      bsum   = cur + NN;                         // 256
    int*      boff   = bsum + 256;                       // 256
    int2*     epair  = (int2*)(boff + 256);              // NE int2 (8B-aligned)
    unsigned* bfrag1 = (unsigned*)(epair + NE);          // 8704
    unsigned* bfrag2 = bfrag1 + 8704;                    // 8704
    float*    msg    = (float*)(bfrag2 + 8704);          // NE*32 (conv1) / NE*16 (conv2)

    // -------- setup (zero cnt/cur, goffs, W fragments) --------
    k_setup<<<512, 256, 0, stream>>>(batch, nn1_w2, nn1_b2, nn2_w2, nn2_b2,
                                     cnt, cur, goffs, bfrag1, bfrag2);

    // -------- fused gate + attention pool --------
    k_gateatt<<<NG, 64, 0, stream>>>(x_p, gw1, gb1, gw2, gb2, goffs, x_att);

    // -------- CSR build over dst --------
    k_hist<<<NE/256, 256, 0, stream>>>(ei, cnt);
    k_scan_blk<<<NN/256, 256, 0, stream>>>(cnt, offs, bsum);
    k_scan_top<<<1, 256, 0, stream>>>(bsum, boff);
    k_scan_add<<<NN/256, 256, 0, stream>>>(offs, boff);
    k_scatter<<<NE/256, 256, 0, stream>>>(ei, offs, cur, epair);

    // -------- conv1 + fused node update --------
    k_conv1<<<2048, 256, 0, stream>>>(x_p, ea_p, epair, nn1_w1, nn1_b1, bfrag1, msg);
    k_reduce1<<<NN*8/256, 256, 0, stream>>>(msg, offs, x_p, root1, bias1, h1);

    // -------- conv2 + fused node update --------
    k_conv2<<<4096, 256, 0, stream>>>(h1, ea_p, epair, nn2_w1, nn2_b1, bfrag2, msg);
    k_reduce2<<<NN*4/256, 256, 0, stream>>>(msg, offs, h1, root2, bias2, h2);

    // -------- head --------
    k_head<<<NG, 64, 0, stream>>>(h2, x_att, goffs, l1w, l1b, l2w, l2b, (float*)d_out);
}